// Round 1
// baseline (516.860 us; speedup 1.0000x reference)
//
#include <hip/hip_runtime.h>

typedef unsigned short u16;
typedef __bf16 bf16x8 __attribute__((ext_vector_type(8)));
typedef float f32x4 __attribute__((ext_vector_type(4)));

// ---------- helpers ----------
__device__ __forceinline__ u16 f2bf(float f) {
  unsigned u = __float_as_uint(f);
  u += 0x7FFF + ((u >> 16) & 1);   // RNE
  return (u16)(u >> 16);
}

__device__ __forceinline__ unsigned pack2(float lo, float hi) {
  return (unsigned)f2bf(lo) | ((unsigned)f2bf(hi) << 16);
}

__device__ __forceinline__ void gload_lds16(const void* g, void* l) {
  __builtin_amdgcn_global_load_lds(
      (const __attribute__((address_space(1))) void*)g,
      (__attribute__((address_space(3))) void*)l,
      16, 0, 0);
}

// ---------- prep: Wv -> bf16, Wofold = sum_h Wo[:, n+1024h] -> bf16 ----------
__global__ void prep_weights(const float* __restrict__ Wv, const float* __restrict__ Wo,
                             uint4* __restrict__ Wvb, uint4* __restrict__ Wofb) {
  const int n8 = (1024 * 4096) / 8;  // 524288 chunks of 8 elements
  int i = blockIdx.x * blockDim.x + threadIdx.x;
  const int stride = gridDim.x * blockDim.x;
  for (; i < 2 * n8; i += stride) {
    if (i < n8) {
      const float4* p = (const float4*)Wv + (size_t)i * 2;
      float4 a = p[0], b = p[1];
      Wvb[i] = make_uint4(pack2(a.x, a.y), pack2(a.z, a.w),
                          pack2(b.x, b.y), pack2(b.z, b.w));
    } else {
      int j = i - n8;            // chunk index into Wofold (4096 x 1024)
      int row = j >> 7;          // 1024/8 = 128 chunks per row
      int c = (j & 127) * 8;
      float4 s0 = {0.f, 0.f, 0.f, 0.f}, s1 = {0.f, 0.f, 0.f, 0.f};
#pragma unroll
      for (int h = 0; h < 4; ++h) {
        const float4* p = (const float4*)(Wo + (size_t)row * 4096 + h * 1024 + c);
        float4 a = p[0], b = p[1];
        s0.x += a.x; s0.y += a.y; s0.z += a.z; s0.w += a.w;
        s1.x += b.x; s1.y += b.y; s1.z += b.z; s1.w += b.w;
      }
      Wofb[j] = make_uint4(pack2(s0.x, s0.y), pack2(s0.z, s0.w),
                           pack2(s1.x, s1.y), pack2(s1.z, s1.w));
    }
  }
}

// ---------- x (f32) -> xb (bf16) ----------
__global__ void cvt_f32_bf16(const float4* __restrict__ in, uint4* __restrict__ out, long n8) {
  long i = (long)blockIdx.x * blockDim.x + threadIdx.x;
  const long stride = (long)gridDim.x * blockDim.x;
  for (; i < n8; i += stride) {
    float4 a = in[i * 2], b = in[i * 2 + 1];
    out[i] = make_uint4(pack2(a.x, a.y), pack2(a.z, a.w),
                        pack2(b.x, b.y), pack2(b.z, b.w));
  }
}

// ---------- NT GEMM: C[M,N] = A[M,K] * B[N,K]^T, bf16 in, f32 acc ----------
// 128x128 tile, BK=64, 4 waves (2x2), 4x4 16x16x32 MFMA tiles per wave.
template<bool OUT_BF16>
__global__ __launch_bounds__(256) void gemm_nt(
    const u16* __restrict__ A, const u16* __restrict__ B, void* __restrict__ Cv,
    int M, int N, int K) {
  __shared__ u16 As[128][64];
  __shared__ u16 Bs[128][64];

  const int tid  = threadIdx.x;
  const int lane = tid & 63;
  const int wave = tid >> 6;
  const int wr = (wave >> 1) * 64;   // wave row offset in tile
  const int wc = (wave & 1) * 64;    // wave col offset in tile

  const int  bn = blockIdx.x, bm = blockIdx.y;
  const long arow0 = (long)bm * 128;
  const long brow0 = (long)bn * 128;

  const int srow = lane >> 3;        // staging: row within 8-row chunk
  const int scol = (lane & 7) * 8;   // staging: bf16 col
  const int klo  = (lane >> 4) * 8;  // fragment k-offset within 32
  const int lm   = lane & 15;        // fragment row/col within 16

  f32x4 acc[4][4];
#pragma unroll
  for (int m = 0; m < 4; ++m)
#pragma unroll
    for (int n = 0; n < 4; ++n) acc[m][n] = {0.f, 0.f, 0.f, 0.f};

  const u16* Ag = A + arow0 * K;
  const u16* Bg = B + brow0 * K;

  for (int k0 = 0; k0 < K; k0 += 64) {
    // stage 128x64 A and B tiles: 16 chunks of 8 rows each, chunk c -> wave c%4
#pragma unroll
    for (int i = 0; i < 4; ++i) {
      const int  c = i * 4 + wave;
      const long r = c * 8 + srow;
      gload_lds16(Ag + r * K + k0 + scol, &As[c * 8][0]);
      gload_lds16(Bg + r * K + k0 + scol, &Bs[c * 8][0]);
    }
    __syncthreads();   // compiler drains vmcnt before barrier

#pragma unroll
    for (int kk = 0; kk < 64; kk += 32) {
      bf16x8 af[4], bfr[4];
#pragma unroll
      for (int m = 0; m < 4; ++m)
        af[m] = *(const bf16x8*)(&As[wr + m * 16 + lm][kk + klo]);
#pragma unroll
      for (int n = 0; n < 4; ++n)
        bfr[n] = *(const bf16x8*)(&Bs[wc + n * 16 + lm][kk + klo]);
#pragma unroll
      for (int m = 0; m < 4; ++m)
#pragma unroll
        for (int n = 0; n < 4; ++n)
          acc[m][n] = __builtin_amdgcn_mfma_f32_16x16x32_bf16(af[m], bfr[n], acc[m][n], 0, 0, 0);
    }
    __syncthreads();
  }

  // epilogue: C/D layout col = lane&15, row = (lane>>4)*4 + r
  const int lr = (lane >> 4) * 4;
#pragma unroll
  for (int m = 0; m < 4; ++m) {
    const long row0 = arow0 + wr + m * 16 + lr;
#pragma unroll
    for (int n = 0; n < 4; ++n) {
      const long col = brow0 + wc + n * 16 + lm;
#pragma unroll
      for (int r = 0; r < 4; ++r) {
        const long idx = (row0 + r) * N + col;
        if constexpr (OUT_BF16) ((u16*)Cv)[idx] = f2bf(acc[m][n][r]);
        else                    ((float*)Cv)[idx] = acc[m][n][r];
      }
    }
  }
}

// ---------- launch ----------
extern "C" void kernel_launch(void* const* d_in, const int* in_sizes, int n_in,
                              void* d_out, int out_size, void* d_ws, size_t ws_size,
                              hipStream_t stream) {
  const float* x  = (const float*)d_in[0];
  // d_in[1] = Wq (dead), d_in[2] = Wk (dead), d_in[5] = mask (dead)
  const float* Wv = (const float*)d_in[3];
  const float* Wo = (const float*)d_in[4];

  const int M = 16384;   // B*S
  const int D = 4096;    // DIM
  const int R = 1024;    // KV_RANK

  // workspace: vb (32MB) + Wvb (8MB) + Wofb (8MB) = 48MB
  u16* vb   = (u16*)d_ws;
  u16* Wvb  = vb + (size_t)M * R;
  u16* Wofb = Wvb + (size_t)R * D;
  // x in bf16 lives in the first 128MB of d_out (dead by the time GEMM2 writes)
  u16* xb   = (u16*)d_out;

  prep_weights<<<dim3(1024), dim3(256), 0, stream>>>(Wv, Wo, (uint4*)Wvb, (uint4*)Wofb);
  cvt_f32_bf16<<<dim3(2048), dim3(256), 0, stream>>>((const float4*)x, (uint4*)xb,
                                                     (long)M * D / 8);
  // v = x @ Wv^T   (M=16384, N=1024, K=4096), bf16 out
  gemm_nt<true><<<dim3(R / 128, M / 128), dim3(256), 0, stream>>>(xb, Wvb, vb, M, R, D);
  // out = v @ Wofold^T (M=16384, N=4096, K=1024), f32 out
  gemm_nt<false><<<dim3(D / 128, M / 128), dim3(256), 0, stream>>>(vb, Wofb, (float*)d_out, M, D, R);
}

// Round 2
// 366.077 us; speedup vs baseline: 1.4119x; 1.4119x over previous
//
#include <hip/hip_runtime.h>

typedef unsigned short u16;
typedef __bf16 bf16x8 __attribute__((ext_vector_type(8)));
typedef float f32x4 __attribute__((ext_vector_type(4)));

// ---------- helpers ----------
__device__ __forceinline__ u16 f2bf(float f) {
  unsigned u = __float_as_uint(f);
  u += 0x7FFF + ((u >> 16) & 1);   // RNE
  return (u16)(u >> 16);
}

__device__ __forceinline__ unsigned pack2(float lo, float hi) {
  return (unsigned)f2bf(lo) | ((unsigned)f2bf(hi) << 16);
}

__device__ __forceinline__ void gload_lds16(const void* g, void* l) {
  __builtin_amdgcn_global_load_lds(
      (const __attribute__((address_space(1))) void*)g,
      (__attribute__((address_space(3))) void*)l,
      16, 0, 0);
}

// T2 swizzle: XOR row&7 into the 16B-slot bits. Involution, 16B-preserving.
__device__ __forceinline__ int swzb(int lin) {
  return lin ^ (((lin >> 7) & 7) << 4);
}

// ---------- prep: Wv -> bf16, Wofold = sum_h Wo[:, n+1024h] -> bf16 ----------
__global__ void prep_weights(const float* __restrict__ Wv, const float* __restrict__ Wo,
                             uint4* __restrict__ Wvb, uint4* __restrict__ Wofb) {
  const int n8 = (1024 * 4096) / 8;
  int i = blockIdx.x * blockDim.x + threadIdx.x;
  const int stride = gridDim.x * blockDim.x;
  for (; i < 2 * n8; i += stride) {
    if (i < n8) {
      const float4* p = (const float4*)Wv + (size_t)i * 2;
      float4 a = p[0], b = p[1];
      Wvb[i] = make_uint4(pack2(a.x, a.y), pack2(a.z, a.w),
                          pack2(b.x, b.y), pack2(b.z, b.w));
    } else {
      int j = i - n8;
      int row = j >> 7;
      int c = (j & 127) * 8;
      float4 s0 = {0.f, 0.f, 0.f, 0.f}, s1 = {0.f, 0.f, 0.f, 0.f};
#pragma unroll
      for (int h = 0; h < 4; ++h) {
        const float4* p = (const float4*)(Wo + (size_t)row * 4096 + h * 1024 + c);
        float4 a = p[0], b = p[1];
        s0.x += a.x; s0.y += a.y; s0.z += a.z; s0.w += a.w;
        s1.x += b.x; s1.y += b.y; s1.z += b.z; s1.w += b.w;
      }
      Wofb[j] = make_uint4(pack2(s0.x, s0.y), pack2(s0.z, s0.w),
                           pack2(s1.x, s1.y), pack2(s1.z, s1.w));
    }
  }
}

// ---------- x (f32) -> xb (bf16) ----------
__global__ void cvt_f32_bf16(const float4* __restrict__ in, uint4* __restrict__ out, long n8) {
  long i = (long)blockIdx.x * blockDim.x + threadIdx.x;
  const long stride = (long)gridDim.x * blockDim.x;
  for (; i < n8; i += stride) {
    float4 a = in[i * 2], b = in[i * 2 + 1];
    out[i] = make_uint4(pack2(a.x, a.y), pack2(a.z, a.w),
                        pack2(b.x, b.y), pack2(b.z, b.w));
  }
}

// ---------- staging: linear LDS dest, inverse-swizzled global source ----------
// Stage one 16KB half (rows [0,128) or [128,256)) of a 256x64 bf16 tile.
__device__ __forceinline__ void stage_half(const char* g, int ldb, char* ldsTile,
                                           int regionBase, int tid) {
#pragma unroll
  for (int j = 0; j < 2; ++j) {
    const int un = regionBase + j * 8192 + (tid >> 6) * 1024;  // wave-uniform
    const int l  = swzb(un + (tid & 63) * 16);                 // per-lane logical byte
    gload_lds16(g + (size_t)(l >> 7) * (size_t)ldb + (l & 127), ldsTile + un);
  }
}

// Stage an interleaved A-half: which=0 -> rows [0,64)+[128,192); which=1 -> [64,128)+[192,256)
__device__ __forceinline__ void stage_Ahalf(const char* g, int ldb, char* ldsA,
                                            int which, int tid) {
#pragma unroll
  for (int j = 0; j < 2; ++j) {
    const int un = (which ? 8192 : 0) + j * 16384 + (tid >> 6) * 1024;
    const int l  = swzb(un + (tid & 63) * 16);
    gload_lds16(g + (size_t)(l >> 7) * (size_t)ldb + (l & 127), ldsA + un);
  }
}

// ---------- one phase: ds_read A quarter, stage, barrier, lgkm, MFMA ----------
template<int P, class Stage>
__device__ __forceinline__ void do_phase(f32x4 (&acc)[8][4], const bf16x8 (&bfr)[4][2],
                                         const char* sA, const int wrow, const int lm,
                                         const int hi16, const int axor, Stage&& stage) {
  bf16x8 afr[2][2];
#pragma unroll
  for (int m2 = 0; m2 < 2; ++m2)
#pragma unroll
    for (int kk = 0; kk < 2; ++kk) {
      const int row = wrow * 128 + (P * 2 + m2) * 16 + lm;
      afr[m2][kk] = *(const bf16x8*)(sA + ((row * 128 + kk * 64 + hi16) ^ axor));
    }
  stage();
  __builtin_amdgcn_s_barrier();
  asm volatile("s_waitcnt lgkmcnt(0)" ::: "memory");
  __builtin_amdgcn_s_setprio(1);
#pragma unroll
  for (int kk = 0; kk < 2; ++kk)
#pragma unroll
    for (int m2 = 0; m2 < 2; ++m2)
#pragma unroll
      for (int ni = 0; ni < 4; ++ni)
        acc[P * 2 + m2][ni] = __builtin_amdgcn_mfma_f32_16x16x32_bf16(
            afr[m2][kk], bfr[ni][kk], acc[P * 2 + m2][ni], 0, 0, 0);
  __builtin_amdgcn_s_setprio(0);
}

// ---------- 256x256 8-phase NT GEMM: C[M,N] = A[M,K] * B[N,K]^T ----------
// 512 threads = 8 waves (2x4). LDS: 2 x (A 32KB | B 32KB) = 128KB dynamic.
template<bool OUT_BF16>
__global__ __launch_bounds__(512, 2) void gemm256(
    const u16* __restrict__ A, const u16* __restrict__ B, void* __restrict__ Cv,
    int M, int N, int K) {
  extern __shared__ char smem[];   // 131072 bytes

  const int tid  = threadIdx.x;
  const int lane = tid & 63;
  const int wave = tid >> 6;
  const int wrow = wave >> 2;      // 0..1
  const int wcol = wave & 3;       // 0..3
  const int lm   = lane & 15;
  const int hi16 = (lane >> 4) * 16;
  const int axor = (lm & 7) << 4;  // swizzle XOR for fragment reads

  // T1: bijective XCD swizzle (grid % 8 == 0 for all our launches)
  const int nwg = gridDim.x;
  const int per = nwg >> 3;
  const int id  = (blockIdx.x & 7) * per + (blockIdx.x >> 3);
  const int nbn = N >> 8;
  const int bm = id / nbn, bn = id % nbn;

  const int ldb = K * 2;           // row stride in bytes (K-contiguous)
  const char* Ab = (const char*)A + (size_t)bm * 256 * (size_t)ldb;
  const char* Bb = (const char*)B + (size_t)bn * 256 * (size_t)ldb;
  const int nt = K >> 6;

  f32x4 acc[8][4];
#pragma unroll
  for (int m = 0; m < 8; ++m)
#pragma unroll
    for (int n = 0; n < 4; ++n) acc[m][n] = {0.f, 0.f, 0.f, 0.f};

  // ---- prologue: tile0 full (8 loads/thr), tile1 B0,B1,A-half1 (6 loads/thr) ----
  {
    char* s0A = smem;            char* s0B = smem + 32768;
    char* s1A = smem + 65536;    char* s1B = s1A + 32768;
    stage_half (Bb, ldb, s0B, 0, tid);
    stage_half (Bb, ldb, s0B, 16384, tid);
    stage_Ahalf(Ab, ldb, s0A, 0, tid);
    stage_Ahalf(Ab, ldb, s0A, 1, tid);
    if (nt > 1) {
      stage_half (Bb + 128, ldb, s1B, 0, tid);
      stage_half (Bb + 128, ldb, s1B, 16384, tid);
      stage_Ahalf(Ab + 128, ldb, s1A, 0, tid);
      asm volatile("s_waitcnt vmcnt(6)" ::: "memory");
    } else {
      asm volatile("s_waitcnt vmcnt(0)" ::: "memory");
    }
    __builtin_amdgcn_s_barrier();
  }

  // ---- main loop: 4 phases per K-tile, counted vmcnt(6), never drain ----
  for (int t = 0; t < nt; ++t) {
    char* sA = smem + (t & 1) * 65536;
    char* sB = sA + 32768;
    char* oA = smem + ((t & 1) ^ 1) * 65536;
    const char* Ag1 = Ab + (size_t)(t + 1) * 128;
    const char* Ag2 = Ab + (size_t)(t + 2) * 128;
    const char* Bg2 = Bb + (size_t)(t + 2) * 128;

    // B fragments for the whole tile (8 x ds_read_b128), held in regs
    bf16x8 bfr[4][2];
#pragma unroll
    for (int ni = 0; ni < 4; ++ni)
#pragma unroll
      for (int kk = 0; kk < 2; ++kk) {
        const int row = wcol * 64 + ni * 16 + lm;
        bfr[ni][kk] = *(const bf16x8*)(sB + ((row * 128 + kk * 64 + hi16) ^ axor));
      }

    do_phase<0>(acc, bfr, sA, wrow, lm, hi16, axor,
                [&] { if (t + 1 < nt) stage_Ahalf(Ag1, ldb, oA, 1, tid); });
    __builtin_amdgcn_s_barrier();
    do_phase<1>(acc, bfr, sA, wrow, lm, hi16, axor,
                [&] { if (t + 2 < nt) stage_half(Bg2, ldb, sB, 0, tid); });
    __builtin_amdgcn_s_barrier();
    do_phase<2>(acc, bfr, sA, wrow, lm, hi16, axor,
                [&] { if (t + 2 < nt) stage_half(Bg2, ldb, sB, 16384, tid); });
    __builtin_amdgcn_s_barrier();
    do_phase<3>(acc, bfr, sA, wrow, lm, hi16, axor,
                [&] { if (t + 2 < nt) stage_Ahalf(Ag2, ldb, sA, 0, tid); });
    if (t + 2 < nt)      asm volatile("s_waitcnt vmcnt(6)" ::: "memory");
    else if (t + 1 < nt) asm volatile("s_waitcnt vmcnt(0)" ::: "memory");
    __builtin_amdgcn_s_barrier();
  }

  // ---- epilogue: C/D layout col = lane&15, row = (lane>>4)*4 + r ----
  const int lr = (lane >> 4) * 4;
#pragma unroll
  for (int m = 0; m < 8; ++m) {
    const long row0 = (long)bm * 256 + wrow * 128 + m * 16 + lr;
#pragma unroll
    for (int ni = 0; ni < 4; ++ni) {
      const long col = (long)bn * 256 + wcol * 64 + ni * 16 + lm;
#pragma unroll
      for (int r = 0; r < 4; ++r) {
        const long idx = (row0 + r) * N + col;
        if constexpr (OUT_BF16) ((u16*)Cv)[idx] = f2bf(acc[m][ni][r]);
        else                    ((float*)Cv)[idx] = acc[m][ni][r];
      }
    }
  }
}

// ---------- launch ----------
extern "C" void kernel_launch(void* const* d_in, const int* in_sizes, int n_in,
                              void* d_out, int out_size, void* d_ws, size_t ws_size,
                              hipStream_t stream) {
  const float* x  = (const float*)d_in[0];
  // d_in[1] = Wq (dead), d_in[2] = Wk (dead), d_in[5] = mask (dead)
  const float* Wv = (const float*)d_in[3];
  const float* Wo = (const float*)d_in[4];

  const int M = 16384;   // B*S
  const int D = 4096;    // DIM
  const int R = 1024;    // KV_RANK

  u16* vb   = (u16*)d_ws;
  u16* Wvb  = vb + (size_t)M * R;
  u16* Wofb = Wvb + (size_t)R * D;
  u16* xb   = (u16*)d_out;   // dead by the time GEMM2 writes d_out

  (void)hipFuncSetAttribute((const void*)gemm256<true>,
                            hipFuncAttributeMaxDynamicSharedMemorySize, 131072);
  (void)hipFuncSetAttribute((const void*)gemm256<false>,
                            hipFuncAttributeMaxDynamicSharedMemorySize, 131072);

  prep_weights<<<dim3(1024), dim3(256), 0, stream>>>(Wv, Wo, (uint4*)Wvb, (uint4*)Wofb);
  cvt_f32_bf16<<<dim3(2048), dim3(256), 0, stream>>>((const float4*)x, (uint4*)xb,
                                                     (long)M * D / 8);
  // v = x @ Wv^T   (M=16384, N=1024, K=4096), bf16 out
  gemm256<true><<<dim3((R / 256) * (M / 256)), dim3(512), 131072, stream>>>(xb, Wvb, vb, M, R, D);
  // out = v @ Wofold^T (M=16384, N=4096, K=1024), f32 out
  gemm256<false><<<dim3((D / 256) * (M / 256)), dim3(512), 131072, stream>>>(vb, Wofb, (float*)d_out, M, D, R);
}

// Round 3
// 363.783 us; speedup vs baseline: 1.4208x; 1.0063x over previous
//
#include <hip/hip_runtime.h>

typedef unsigned short u16;
typedef __bf16 bf16x8 __attribute__((ext_vector_type(8)));
typedef float f32x4 __attribute__((ext_vector_type(4)));

// ---------- helpers ----------
__device__ __forceinline__ u16 f2bf(float f) {
  unsigned u = __float_as_uint(f);
  u += 0x7FFF + ((u >> 16) & 1);   // RNE
  return (u16)(u >> 16);
}

__device__ __forceinline__ unsigned pack2(float lo, float hi) {
  return (unsigned)f2bf(lo) | ((unsigned)f2bf(hi) << 16);
}

__device__ __forceinline__ void gload_lds16(const void* g, void* l) {
  __builtin_amdgcn_global_load_lds(
      (const __attribute__((address_space(1))) void*)g,
      (__attribute__((address_space(3))) void*)l,
      16, 0, 0);
}

// T2 swizzle: XOR row&7 into the 16B-slot bits. Involution, 16B-preserving.
__device__ __forceinline__ int swzb(int lin) {
  return lin ^ (((lin >> 7) & 7) << 4);
}

// ---------- fused prep: x->bf16, Wv->bf16, Wofold = sum_h Wo[:, n+1024h] ----------
__global__ void prep_all(const float4* __restrict__ x, const float* __restrict__ Wv,
                         const float* __restrict__ Wo, uint4* __restrict__ xb,
                         uint4* __restrict__ Wvb, uint4* __restrict__ Wofb) {
  const int nx = (16384 * 4096) / 8;   // 8388608
  const int nw = (1024 * 4096) / 8;    // 524288
  int i = blockIdx.x * blockDim.x + threadIdx.x;
  const int stride = gridDim.x * blockDim.x;
  for (; i < nx + 2 * nw; i += stride) {
    if (i < nx) {
      float4 a = x[(size_t)i * 2], b = x[(size_t)i * 2 + 1];
      xb[i] = make_uint4(pack2(a.x, a.y), pack2(a.z, a.w),
                         pack2(b.x, b.y), pack2(b.z, b.w));
    } else if (i < nx + nw) {
      int j = i - nx;
      const float4* p = (const float4*)Wv + (size_t)j * 2;
      float4 a = p[0], b = p[1];
      Wvb[j] = make_uint4(pack2(a.x, a.y), pack2(a.z, a.w),
                          pack2(b.x, b.y), pack2(b.z, b.w));
    } else {
      int j = i - nx - nw;
      int row = j >> 7;
      int c = (j & 127) * 8;
      float4 s0 = {0.f, 0.f, 0.f, 0.f}, s1 = {0.f, 0.f, 0.f, 0.f};
#pragma unroll
      for (int h = 0; h < 4; ++h) {
        const float4* p = (const float4*)(Wo + (size_t)row * 4096 + h * 1024 + c);
        float4 a = p[0], b = p[1];
        s0.x += a.x; s0.y += a.y; s0.z += a.z; s0.w += a.w;
        s1.x += b.x; s1.y += b.y; s1.z += b.z; s1.w += b.w;
      }
      Wofb[j] = make_uint4(pack2(s0.x, s0.y), pack2(s0.z, s0.w),
                           pack2(s1.x, s1.y), pack2(s1.z, s1.w));
    }
  }
}

// ---------- staging: linear LDS dest, inverse-swizzled global source ----------
__device__ __forceinline__ void stage_half(const char* g, int ldb, char* ldsTile,
                                           int regionBase, int tid) {
#pragma unroll
  for (int j = 0; j < 2; ++j) {
    const int un = regionBase + j * 8192 + (tid >> 6) * 1024;  // wave-uniform
    const int l  = swzb(un + (tid & 63) * 16);                 // per-lane logical byte
    gload_lds16(g + (size_t)(l >> 7) * (size_t)ldb + (l & 127), ldsTile + un);
  }
}

// which=0 -> rows [0,64)+[128,192); which=1 -> [64,128)+[192,256)
__device__ __forceinline__ void stage_Ahalf(const char* g, int ldb, char* ldsA,
                                            int which, int tid) {
#pragma unroll
  for (int j = 0; j < 2; ++j) {
    const int un = (which ? 8192 : 0) + j * 16384 + (tid >> 6) * 1024;
    const int l  = swzb(un + (tid & 63) * 16);
    gload_lds16(g + (size_t)(l >> 7) * (size_t)ldb + (l & 127), ldsA + un);
  }
}

// ---------- one phase: ds_read A quarter, stage, barrier, lgkm, MFMA ----------
template<int P, class Stage>
__device__ __forceinline__ void do_phase(f32x4 (&acc)[8][4], const bf16x8 (&bfr)[4][2],
                                         const char* sA, const int wrow, const int lm,
                                         const int hi16, const int axor, Stage&& stage) {
  bf16x8 afr[2][2];
#pragma unroll
  for (int m2 = 0; m2 < 2; ++m2)
#pragma unroll
    for (int kk = 0; kk < 2; ++kk) {
      const int row = wrow * 128 + (P * 2 + m2) * 16 + lm;
      afr[m2][kk] = *(const bf16x8*)(sA + ((row * 128 + kk * 64 + hi16) ^ axor));
    }
  stage();
  __builtin_amdgcn_s_barrier();
  asm volatile("s_waitcnt lgkmcnt(0)" ::: "memory");
  __builtin_amdgcn_s_setprio(1);
#pragma unroll
  for (int kk = 0; kk < 2; ++kk)
#pragma unroll
    for (int m2 = 0; m2 < 2; ++m2)
#pragma unroll
      for (int ni = 0; ni < 4; ++ni)
        acc[P * 2 + m2][ni] = __builtin_amdgcn_mfma_f32_16x16x32_bf16(
            afr[m2][kk], bfr[ni][kk], acc[P * 2 + m2][ni], 0, 0, 0);
  __builtin_amdgcn_s_setprio(0);
}

// ---------- persistent 256x256 8-phase NT GEMM: C[M,N] = A[M,K] * B[N,K]^T ----------
// Grid MUST be 256 blocks of 512 threads. Each block computes REPS output tiles.
template<bool OUT_BF16, int REPS>
__global__ __launch_bounds__(512, 2) void gemm256(
    const u16* __restrict__ A, const u16* __restrict__ B, void* __restrict__ Cv,
    int M, int N, int K) {
  extern __shared__ char smem[];   // 131072 bytes

  const int tid  = threadIdx.x;
  const int lane = tid & 63;
  const int wave = tid >> 6;
  const int wrow = wave >> 2;      // 0..1
  const int wcol = wave & 3;       // 0..3
  const int lm   = lane & 15;
  const int hi16 = (lane >> 4) * 16;
  const int axor = (lm & 7) << 4;

  // T1: bijective XCD swizzle over a 256-block grid (per-XCD chunk = 32)
  const int swzid = (blockIdx.x & 7) * 32 + (blockIdx.x >> 3);
  const int nbn = N >> 8;
  const int ldb = K * 2;
  const int nt  = K >> 6;

#pragma unroll 1
  for (int rep = 0; rep < REPS; ++rep) {
    const int id = rep * 256 + swzid;
    const int bm = id / nbn, bn = id % nbn;
    const char* Ab = (const char*)A + (size_t)bm * 256 * (size_t)ldb;
    const char* Bb = (const char*)B + (size_t)bn * 256 * (size_t)ldb;

    f32x4 acc[8][4];
#pragma unroll
    for (int m = 0; m < 8; ++m)
#pragma unroll
      for (int n = 0; n < 4; ++n) acc[m][n] = {0.f, 0.f, 0.f, 0.f};

    // ---- prologue: tile0 full (8 loads/thr), tile1 B0,B1,A-half0 (6 loads/thr) ----
    {
      char* s0A = smem;            char* s0B = smem + 32768;
      char* s1A = smem + 65536;    char* s1B = s1A + 32768;
      stage_half (Bb, ldb, s0B, 0, tid);
      stage_half (Bb, ldb, s0B, 16384, tid);
      stage_Ahalf(Ab, ldb, s0A, 0, tid);
      stage_Ahalf(Ab, ldb, s0A, 1, tid);
      if (nt > 1) {
        stage_half (Bb + 128, ldb, s1B, 0, tid);
        stage_half (Bb + 128, ldb, s1B, 16384, tid);
        stage_Ahalf(Ab + 128, ldb, s1A, 0, tid);
        asm volatile("s_waitcnt vmcnt(6)" ::: "memory");
      } else {
        asm volatile("s_waitcnt vmcnt(0)" ::: "memory");
      }
      __builtin_amdgcn_s_barrier();
    }

    // ---- main loop: 4 phases per K-tile, counted vmcnt(6), never drain ----
#pragma unroll 1
    for (int t = 0; t < nt; ++t) {
      char* sA = smem + (t & 1) * 65536;
      char* sB = sA + 32768;
      char* oA = smem + ((t & 1) ^ 1) * 65536;
      const char* Ag1 = Ab + (size_t)(t + 1) * 128;
      const char* Ag2 = Ab + (size_t)(t + 2) * 128;
      const char* Bg2 = Bb + (size_t)(t + 2) * 128;

      // B fragments for the whole tile (8 x ds_read_b128), held in regs
      bf16x8 bfr[4][2];
#pragma unroll
      for (int ni = 0; ni < 4; ++ni)
#pragma unroll
        for (int kk = 0; kk < 2; ++kk) {
          const int row = wcol * 64 + ni * 16 + lm;
          bfr[ni][kk] = *(const bf16x8*)(sB + ((row * 128 + kk * 64 + hi16) ^ axor));
        }

      do_phase<0>(acc, bfr, sA, wrow, lm, hi16, axor,
                  [&] { if (t + 1 < nt) stage_Ahalf(Ag1, ldb, oA, 1, tid); });
      __builtin_amdgcn_s_barrier();
      do_phase<1>(acc, bfr, sA, wrow, lm, hi16, axor,
                  [&] { if (t + 2 < nt) stage_half(Bg2, ldb, sB, 0, tid); });
      __builtin_amdgcn_s_barrier();
      do_phase<2>(acc, bfr, sA, wrow, lm, hi16, axor,
                  [&] { if (t + 2 < nt) stage_half(Bg2, ldb, sB, 16384, tid); });
      __builtin_amdgcn_s_barrier();
      do_phase<3>(acc, bfr, sA, wrow, lm, hi16, axor,
                  [&] { if (t + 2 < nt) stage_Ahalf(Ag2, ldb, sA, 0, tid); });
      if (t + 2 < nt)      asm volatile("s_waitcnt vmcnt(6)" ::: "memory");
      else if (t + 1 < nt) asm volatile("s_waitcnt vmcnt(0)" ::: "memory");
      __builtin_amdgcn_s_barrier();
    }

    // ---- epilogue: C/D layout col = lane&15, row = (lane>>4)*4 + r ----
    const int lr = (lane >> 4) * 4;
#pragma unroll
    for (int m = 0; m < 8; ++m) {
      const long row0 = (long)bm * 256 + wrow * 128 + m * 16 + lr;
#pragma unroll
      for (int ni = 0; ni < 4; ++ni) {
        const long col = (long)bn * 256 + wcol * 64 + ni * 16 + lm;
#pragma unroll
        for (int r = 0; r < 4; ++r) {
          const long idx = (row0 + r) * N + col;
          if constexpr (OUT_BF16) ((u16*)Cv)[idx] = f2bf(acc[m][ni][r]);
          else                    ((float*)Cv)[idx] = acc[m][ni][r];
        }
      }
    }
  }
}

// ---------- launch ----------
extern "C" void kernel_launch(void* const* d_in, const int* in_sizes, int n_in,
                              void* d_out, int out_size, void* d_ws, size_t ws_size,
                              hipStream_t stream) {
  const float* x  = (const float*)d_in[0];
  // d_in[1] = Wq (dead), d_in[2] = Wk (dead), d_in[5] = mask (dead)
  const float* Wv = (const float*)d_in[3];
  const float* Wo = (const float*)d_in[4];

  const int M = 16384;   // B*S
  const int D = 4096;    // DIM
  const int R = 1024;    // KV_RANK

  u16* vb   = (u16*)d_ws;
  u16* Wvb  = vb + (size_t)M * R;
  u16* Wofb = Wvb + (size_t)R * D;
  u16* xb   = (u16*)d_out;   // dead by the time GEMM2 writes d_out

  (void)hipFuncSetAttribute((const void*)gemm256<true, 1>,
                            hipFuncAttributeMaxDynamicSharedMemorySize, 131072);
  (void)hipFuncSetAttribute((const void*)gemm256<false, 4>,
                            hipFuncAttributeMaxDynamicSharedMemorySize, 131072);

  prep_all<<<dim3(2048), dim3(256), 0, stream>>>((const float4*)x, Wv, Wo,
                                                 (uint4*)xb, (uint4*)Wvb, (uint4*)Wofb);
  // v = x @ Wv^T   (M=16384, N=1024, K=4096): 256 tiles, 1 rep
  gemm256<true, 1><<<dim3(256), dim3(512), 131072, stream>>>(xb, Wvb, vb, M, R, D);
  // out = v @ Wofold^T (M=16384, N=4096, K=1024): 1024 tiles, persistent 4 reps
  gemm256<false, 4><<<dim3(256), dim3(512), 131072, stream>>>(vb, Wofb, (float*)d_out, M, D, R);
}